// Round 1
// baseline (272.914 us; speedup 1.0000x reference)
//
#include <hip/hip_runtime.h>
#include <hip/hip_bf16.h>
#include <stdint.h>

// Greedy flat span-NMS decoder.
// B blocks (one per batch), 1024 threads. Phase 1: build sortable u64 keys
// ((sortable float bits)<<13 | idx) and bitonic-sort 8192 of them in LDS.
// Phase 2: wave 0 walks the sorted list 64 candidates at a time with a
// 512-bit coverage bitmap in registers; ballot/ffs picks the next kept
// candidate (sequential-greedy equivalent since conflict is monotone).

#define NSPAN 1024
#define NENT  8
#define NCAND (NSPAN * NENT)   // 8192
#define THREADS 1024

__global__ __launch_bounds__(THREADS)
void decoder_kernel(const float* __restrict__ gprobs,
                    const int* __restrict__ gspans,
                    float* __restrict__ gout) {
    __shared__ uint64_t keys[NCAND];      // 64 KiB
    __shared__ uint32_t spanse[NSPAN];    // 4 KiB: start | end<<16

    const int tid = threadIdx.x;
    const int b = blockIdx.x;

    // ---- load + build keys ----
    const float* probs = gprobs + (size_t)b * NCAND;
    for (int i = tid; i < NCAND; i += THREADS) {
        float p = probs[i];
        bool valid = p > 0.5f;
        float fkey = valid ? -p : __builtin_inff();
        uint32_t u = __float_as_uint(fkey);
        // monotone float->uint mapping (ascending uint == ascending float)
        u = (u & 0x80000000u) ? ~u : (u | 0x80000000u);
        keys[i] = ((uint64_t)u << 13) | (uint32_t)i;   // idx in low 13 bits => stable
    }
    {
        int s = gspans[(size_t)b * NSPAN * 2 + 2 * tid];
        int e = gspans[(size_t)b * NSPAN * 2 + 2 * tid + 1];
        spanse[tid] = (uint32_t)s | ((uint32_t)e << 16);
    }
    __syncthreads();

    // ---- bitonic sort ascending (8192 u64 keys) ----
    for (int k = 2; k <= NCAND; k <<= 1) {
        for (int j = k >> 1; j > 0; j >>= 1) {
            for (int i = tid; i < NCAND; i += THREADS) {
                int ixj = i ^ j;
                if (ixj > i) {
                    uint64_t a = keys[i];
                    uint64_t c = keys[ixj];
                    bool up = ((i & k) == 0);
                    bool sw = up ? (a > c) : (a < c);
                    if (sw) { keys[i] = c; keys[ixj] = a; }
                }
            }
            __syncthreads();
        }
    }

    // ---- greedy suppression: wave 0 only ----
    if (tid < 64) {
        const int lane = tid;
        uint64_t bitmap[8] = {0, 0, 0, 0, 0, 0, 0, 0};
        float* out = gout + (size_t)b * NCAND;

        for (int chunk = 0; chunk < NCAND / 64; ++chunk) {
            int i = chunk * 64 + lane;
            uint64_t key = keys[i];
            uint32_t u = (uint32_t)(key >> 13);
            int idx = (int)(key & (NCAND - 1));
            bool valid = (u & 0x80000000u) == 0;   // only finite-negative keys valid
            float score = 0.0f;
            if (valid) score = -__uint_as_float(~u);

            uint32_t se = spanse[idx >> 3];
            int s = (int)(se & 0xFFFFu);
            int e = (int)(se >> 16);
            int w0 = s >> 6, w1 = e >> 6;           // e-s <= 10 -> w1 <= w0+1
            uint64_t m0 = (~0ull) << (s & 63);
            uint64_t m1 = (~0ull) >> (63 - (e & 63));
            if (w0 == w1) { m0 &= m1; m1 = 0ull; }

            bool decided = !valid;   // invalid: rejected immediately, no bitmap effect
            bool keep = false;

            while (true) {
                // conflict vs current bitmap (unrolled to avoid dyn reg indexing)
                uint64_t c = 0;
                #pragma unroll
                for (int w = 0; w < 8; ++w) {
                    uint64_t bm = bitmap[w];
                    if (w == w0) c |= bm & m0;
                    if (w1 != w0 && w == w1) c |= bm & m1;
                }
                bool conflict = (c != 0);

                uint64_t pend = __ballot(!decided);
                if (pend == 0ull) break;
                uint64_t cand = __ballot(!decided && !conflict);
                if (cand == 0ull) break;  // all remaining pending conflict -> rejected

                int jl = __ffsll((unsigned long long)cand) - 1;
                // all pending lanes < jl conflict with the *current* bitmap and
                // nothing is inserted before their turn -> rejected; jl is kept.
                if (!decided && lane <= jl) {
                    decided = true;
                    if (lane == jl) keep = true;
                }
                // broadcast winner's interval, grow the bitmap on every lane
                int bw0 = __shfl(w0, jl);
                int bw1 = __shfl(w1, jl);
                uint64_t bm0 = (uint64_t)__shfl((unsigned long long)m0, jl);
                uint64_t bm1 = (uint64_t)__shfl((unsigned long long)m1, jl);
                #pragma unroll
                for (int w = 0; w < 8; ++w) {
                    if (w == bw0) bitmap[w] |= bm0;
                    if (bw1 != bw0 && w == bw1) bitmap[w] |= bm1;
                }
            }

            out[i] = keep ? score : 0.0f;
        }
    }
}

extern "C" void kernel_launch(void* const* d_in, const int* in_sizes, int n_in,
                              void* d_out, int out_size, void* d_ws, size_t ws_size,
                              hipStream_t stream) {
    const float* probs = (const float*)d_in[0];
    const int* spans = (const int*)d_in[1];
    float* out = (float*)d_out;
    int B = in_sizes[0] / NCAND;   // 4
    decoder_kernel<<<dim3(B), dim3(THREADS), 0, stream>>>(probs, spans, out);
}

// Round 2
// 197.036 us; speedup vs baseline: 1.3851x; 1.3851x over previous
//
#include <hip/hip_runtime.h>
#include <hip/hip_bf16.h>
#include <stdint.h>

// Greedy flat span-NMS decoder, round 2.
// One block per batch, 1024 threads. Sort: hybrid bitonic — each thread owns
// 8 contiguous elements in registers; strides 1/2/4 in-register, strides
// 8..256 via __shfl_xor (no barriers), strides >=512 via transposed LDS
// (conflict-free, 2 barriers each, only 10 such phases). Greedy: wave 0,
// 512-bit coverage bitmap + ballot, incremental conflict accumulation,
// early-exit zero fill for the invalid suffix.

#define NSPAN 1024
#define NENT  8
#define NCAND (NSPAN * NENT)   // 8192
#define THREADS 1024

// branch-free compare-exchange: ascending puts min in x
#define CMPSWAP(x, y, asc) {                          \
    uint64_t _a = (x), _b = (y);                      \
    uint64_t _mn = (_a < _b) ? _a : _b;               \
    uint64_t _mx = (_a < _b) ? _b : _a;               \
    (x) = (asc) ? _mn : _mx;                          \
    (y) = (asc) ? _mx : _mn;                          \
}

__global__ __launch_bounds__(THREADS)
void decoder_kernel(const float* __restrict__ gprobs,
                    const int* __restrict__ gspans,
                    float* __restrict__ gout) {
    __shared__ uint64_t keys[NCAND];      // 64 KiB (transposed during sort)
    __shared__ uint32_t spanse[NSPAN];    // 4 KiB: start | end<<16

    const int tid = threadIdx.x;
    const int b = blockIdx.x;
    const int base = tid * 8;

    // ---- load spans ----
    {
        int s = gspans[(size_t)b * NSPAN * 2 + 2 * tid];
        int e = gspans[(size_t)b * NSPAN * 2 + 2 * tid + 1];
        spanse[tid] = (uint32_t)s | ((uint32_t)e << 16);
    }

    // ---- build keys in registers (8 contiguous candidates per thread) ----
    uint64_t r[8];
    const float* probs = gprobs + (size_t)b * NCAND;
    const float4* p4 = (const float4*)probs;
    float4 pa = p4[tid * 2];
    float4 pb = p4[tid * 2 + 1];
    float pv[8] = {pa.x, pa.y, pa.z, pa.w, pb.x, pb.y, pb.z, pb.w};
    #pragma unroll
    for (int s = 0; s < 8; ++s) {
        float p = pv[s];
        bool valid = p > 0.5f;
        // monotone sortable mapping of (valid ? -p : +inf):
        //   -p is negative -> ~bits(-p) (< 0x80000000); +inf -> 0xFF800000
        uint32_t u = valid ? ~__float_as_uint(-p) : 0xFF800000u;
        r[s] = ((uint64_t)u << 13) | (uint32_t)(base + s);
    }

    // ---- hybrid bitonic sort ascending over 8192 u64 keys ----
    for (int k = 2; k <= NCAND; k <<= 1) {
        // cross-wave strides: j >= 512 (partner thread differs in bits >= 64)
        for (int j = k >> 1; j >= 512; j >>= 1) {
            int m = j >> 3;                        // 64..512
            #pragma unroll
            for (int s = 0; s < 8; ++s) keys[s * 1024 + tid] = r[s];
            __syncthreads();
            int pr = tid ^ m;
            bool lower = (tid & m) == 0;
            bool asc = (tid & (k >> 3)) == 0;
            bool keepmin = (lower == asc);
            #pragma unroll
            for (int s = 0; s < 8; ++s) {
                uint64_t o = keys[s * 1024 + pr];
                uint64_t mn = (r[s] < o) ? r[s] : o;
                uint64_t mx = (r[s] < o) ? o : r[s];
                r[s] = keepmin ? mn : mx;
            }
            __syncthreads();
        }
        // in-wave strides: 8 <= j <= 256 via shfl_xor, no barriers
        for (int j = ((k >> 1) < 256 ? (k >> 1) : 256); j >= 8; j >>= 1) {
            int m = j >> 3;                        // 1..32
            bool lower = (tid & m) == 0;
            bool asc = (tid & (k >> 3)) == 0;      // k >= 16 here
            bool keepmin = (lower == asc);
            #pragma unroll
            for (int s = 0; s < 8; ++s) {
                uint64_t o = (uint64_t)__shfl_xor((unsigned long long)r[s], m, 64);
                uint64_t mn = (r[s] < o) ? r[s] : o;
                uint64_t mx = (r[s] < o) ? o : r[s];
                r[s] = keepmin ? mn : mx;
            }
        }
        // in-register strides j = 4, 2, 1
        if (k >= 8) {
            #pragma unroll
            for (int s = 0; s < 4; ++s) {
                bool asc = (((base + s) & k) == 0);
                CMPSWAP(r[s], r[s + 4], asc);
            }
        }
        if (k >= 4) {
            #pragma unroll
            for (int g = 0; g < 2; ++g)
                #pragma unroll
                for (int s = 0; s < 2; ++s) {
                    int a = g * 4 + s;
                    bool asc = (((base + a) & k) == 0);
                    CMPSWAP(r[a], r[a + 2], asc);
                }
        }
        {
            #pragma unroll
            for (int g = 0; g < 4; ++g) {
                int a = g * 2;
                bool asc = (((base + a) & k) == 0);
                CMPSWAP(r[a], r[a + 1], asc);
            }
        }
    }

    // ---- publish sorted order for the greedy wave ----
    #pragma unroll
    for (int s = 0; s < 8; ++s) keys[base + s] = r[s];
    __syncthreads();

    // ---- greedy suppression: wave 0 only ----
    if (tid < 64) {
        const int lane = tid;
        uint64_t bitmap[8] = {0, 0, 0, 0, 0, 0, 0, 0};
        float* out = gout + (size_t)b * NCAND;

        int chunk = 0;
        for (; chunk < NCAND / 64; ++chunk) {
            int i = chunk * 64 + lane;
            uint64_t key = keys[i];
            uint32_t u = (uint32_t)(key >> 13);
            int idx = (int)(key & (NCAND - 1));
            bool valid = (u & 0x80000000u) == 0;
            if (__ballot(valid) == 0ull) break;   // sorted: suffix all invalid
            float score = 0.0f;
            if (valid) score = -__uint_as_float(~u);

            uint32_t se = spanse[idx >> 3];
            int s = (int)(se & 0xFFFFu);
            int e = (int)(se >> 16);
            int w0 = s >> 6, w1 = e >> 6;          // width <= 10 -> w1 <= w0+1
            uint64_t m0 = (~0ull) << (s & 63);
            uint64_t m1 = (~0ull) >> (63 - (e & 63));
            if (w0 == w1) { m0 &= m1; m1 = 0ull; }

            // incremental conflict vs current coverage
            uint64_t conf = 0;
            #pragma unroll
            for (int w = 0; w < 8; ++w) {
                uint64_t bm = bitmap[w];
                if (w == w0) conf |= bm & m0;
                if (w1 != w0 && w == w1) conf |= bm & m1;
            }

            bool decided = !valid;
            bool keep = false;

            while (true) {
                uint64_t pend = __ballot(!decided);
                if (pend == 0ull) break;
                uint64_t cand = __ballot(!decided && (conf == 0ull));
                if (cand == 0ull) break;   // all pending conflict -> rejected

                int jl = __ffsll((unsigned long long)cand) - 1;
                if (!decided && lane <= jl) {
                    decided = true;
                    if (lane == jl) keep = true;
                }
                int bw0 = __shfl(w0, jl);
                int bw1 = __shfl(w1, jl);
                uint64_t bm0 = (uint64_t)__shfl((unsigned long long)m0, jl);
                uint64_t bm1 = (uint64_t)__shfl((unsigned long long)m1, jl);
                #pragma unroll
                for (int w = 0; w < 8; ++w) {
                    uint64_t add = 0;
                    if (w == bw0) add |= bm0;
                    if (bw1 != bw0 && w == bw1) add |= bm1;
                    if (add) {
                        bitmap[w] |= add;
                        if (w == w0) conf |= add & m0;
                        if (w1 != w0 && w == w1) conf |= add & m1;
                    }
                }
            }

            out[i] = keep ? score : 0.0f;
        }

        // vectorized zero fill for the all-invalid suffix
        float4 z = make_float4(0.f, 0.f, 0.f, 0.f);
        float4* out4 = (float4*)out;
        for (int i4 = chunk * 16 + lane; i4 < NCAND / 4; i4 += 64) out4[i4] = z;
    }
}

extern "C" void kernel_launch(void* const* d_in, const int* in_sizes, int n_in,
                              void* d_out, int out_size, void* d_ws, size_t ws_size,
                              hipStream_t stream) {
    const float* probs = (const float*)d_in[0];
    const int* spans = (const int*)d_in[1];
    float* out = (float*)d_out;
    int B = in_sizes[0] / NCAND;   // 4
    decoder_kernel<<<dim3(B), dim3(THREADS), 0, stream>>>(probs, spans, out);
}

// Round 3
// 125.528 us; speedup vs baseline: 2.1741x; 1.5697x over previous
//
#include <hip/hip_runtime.h>
#include <stdint.h>

// Greedy flat span-NMS decoder, round 3.
// One block per batch, 1024 threads.
// Sort: 3-pass stable LSD radix (8-bit digits) over a 24-bit key
//   key = valid ? (~bits(-p) - 0x407FFFFF) : 0xFFFFFF   (ascending = desc score)
//   u32 key + u16 original-index payload, ping-pong in LDS.
//   Ranking: per-wave hist + 8-ballot digit match (stable -> exact argsort).
// Greedy: wave 0, scalar (wave-uniform) 512-bit coverage bitmap, winner span
//   broadcast via one v_readlane of packed se, se[] pre-gathered per sorted
//   position by all 1024 threads (no dependent load chain in the hot loop).

#define NSPAN 1024
#define NENT  8
#define NCAND 8192
#define THREADS 1024
#define NWAVE 16

__global__ __launch_bounds__(THREADS)
void decoder_kernel(const float* __restrict__ gprobs,
                    const int* __restrict__ gspans,
                    float* __restrict__ gout) {
    __shared__ uint32_t keyA[NCAND];     // 32 KiB (later reused as se[] per sorted pos)
    __shared__ uint32_t keyB[NCAND];     // 32 KiB
    __shared__ uint16_t idxA[NCAND];     // 16 KiB
    __shared__ uint16_t idxB[NCAND];     // 16 KiB
    __shared__ uint16_t lrank[NCAND];    // 16 KiB
    __shared__ uint16_t hist[NWAVE * 256]; // 8 KiB  hist[W*256+d]
    __shared__ uint32_t spanse[NSPAN];   // 4 KiB  start | end<<16
    __shared__ uint32_t wsum[NWAVE], wsex[NWAVE];
    __shared__ uint32_t nvpart[NWAVE];
    __shared__ uint32_t nvsh;

    const int tid = threadIdx.x;
    const int b = blockIdx.x;
    const int W = tid >> 6;
    const int L = tid & 63;

    // ---- spans ----
    {
        int s = gspans[(size_t)b * NSPAN * 2 + 2 * tid];
        int e = gspans[(size_t)b * NSPAN * 2 + 2 * tid + 1];
        spanse[tid] = (uint32_t)s | ((uint32_t)e << 16);
    }

    // ---- build 24-bit keys + idx payload ----
    const float* probs = gprobs + (size_t)b * NCAND;
    const float4* p4 = (const float4*)probs;
    float4 pa = p4[tid * 2];
    float4 pb = p4[tid * 2 + 1];
    float pv[8] = {pa.x, pa.y, pa.z, pa.w, pb.x, pb.y, pb.z, pb.w};
    int vcnt = 0;
    #pragma unroll
    for (int s = 0; s < 8; ++s) {
        float p = pv[s];
        bool valid = p > 0.5f;
        uint32_t u = ~__float_as_uint(-p);                 // valid: in [0x407FFFFF, 0x40FFFFFE]
        uint32_t k = valid ? (u - 0x407FFFFFu) : 0x00FFFFFFu;
        keyA[tid * 8 + s] = k;
        idxA[tid * 8 + s] = (uint16_t)(tid * 8 + s);
        vcnt += valid ? 1 : 0;
    }
    {   // count valid per wave (no atomics needed)
        int x = vcnt;
        #pragma unroll
        for (int off = 32; off; off >>= 1) x += __shfl_down(x, off, 64);
        if (L == 0) nvpart[W] = (uint32_t)x;
    }
    __syncthreads();
    if (tid == 0) {
        uint32_t t = 0;
        for (int w = 0; w < NWAVE; ++w) t += nvpart[w];
        nvsh = t;
    }

    // ---- 3-pass stable LSD radix sort (8-bit digits, 24-bit key) ----
    uint32_t* ks = keyA; uint32_t* kd = keyB;
    uint16_t* is = idxA; uint16_t* id = idxB;
    for (int p = 0; p < 3; ++p) {
        const int sh = 8 * p;
        // zero hist
        #pragma unroll
        for (int q = 0; q < 4; ++q) hist[q * 1024 + tid] = 0;
        __syncthreads();

        // Phase A: digits, per-wave hist, stable local ranks.
        // element position = W*512 + j*64 + L  (wave-major, round-major, lane)
        uint32_t myk[8]; uint32_t myd[8];
        #pragma unroll
        for (int j = 0; j < 8; ++j) myk[j] = ks[W * 512 + j * 64 + L];
        #pragma unroll
        for (int j = 0; j < 8; ++j) {
            uint32_t d = (myk[j] >> sh) & 255u;
            myd[j] = d;
            uint64_t m = ~0ull;
            #pragma unroll
            for (int bb = 0; bb < 8; ++bb) {
                uint64_t bal = __ballot((d >> bb) & 1u);
                m &= ((d >> bb) & 1u) ? bal : ~bal;
            }
            uint32_t lower = __builtin_amdgcn_mbcnt_hi((uint32_t)(m >> 32),
                             __builtin_amdgcn_mbcnt_lo((uint32_t)m, 0));
            uint32_t prev = hist[W * 256 + d];             // sum of earlier rounds
            lrank[W * 512 + j * 64 + L] = (uint16_t)(prev + lower);
            if (lower == 0)                                // digit-group leader
                hist[W * 256 + d] = (uint16_t)(prev + (uint32_t)__popcll(m));
        }
        __syncthreads();

        // Phase B: exclusive scan of hist in (digit-major, wave) order.
        {
            int s0 = 4 * tid;
            uint32_t v0 = hist[((s0 + 0) & 15) * 256 + ((s0 + 0) >> 4)];
            uint32_t v1 = hist[((s0 + 1) & 15) * 256 + ((s0 + 1) >> 4)];
            uint32_t v2 = hist[((s0 + 2) & 15) * 256 + ((s0 + 2) >> 4)];
            uint32_t v3 = hist[((s0 + 3) & 15) * 256 + ((s0 + 3) >> 4)];
            uint32_t t01 = v0 + v1, t012 = t01 + v2, tot = t012 + v3;
            uint32_t x = tot;
            #pragma unroll
            for (int off = 1; off < 64; off <<= 1) {
                uint32_t y = __shfl_up(x, off, 64);
                if (L >= off) x += y;
            }
            if (L == 63) wsum[W] = x;
            __syncthreads();
            if (tid == 0) {
                uint32_t a = 0;
                for (int w = 0; w < NWAVE; ++w) { wsex[w] = a; a += wsum[w]; }
            }
            __syncthreads();
            uint32_t ex = wsex[W] + (x - tot);             // exclusive prefix of this thread
            hist[((s0 + 0) & 15) * 256 + ((s0 + 0) >> 4)] = (uint16_t)ex;
            hist[((s0 + 1) & 15) * 256 + ((s0 + 1) >> 4)] = (uint16_t)(ex + v0);
            hist[((s0 + 2) & 15) * 256 + ((s0 + 2) >> 4)] = (uint16_t)(ex + t01);
            hist[((s0 + 3) & 15) * 256 + ((s0 + 3) >> 4)] = (uint16_t)(ex + t012);
        }
        __syncthreads();

        // Phase C: scatter
        #pragma unroll
        for (int j = 0; j < 8; ++j) {
            int pos = W * 512 + j * 64 + L;
            uint32_t addr = (uint32_t)hist[W * 256 + myd[j]] + (uint32_t)lrank[pos];
            kd[addr] = myk[j];
            id[addr] = is[pos];
        }
        __syncthreads();
        uint32_t* tk = ks; ks = kd; kd = tk;
        uint16_t* ti = is; is = id; id = ti;
    }
    // final sorted arrays: ks == keyB, is == idxB

    // ---- pre-gather se per sorted position (into keyA, now free) + zero fill ----
    const uint32_t nv = nvsh;
    float* out = gout + (size_t)b * NCAND;
    for (int i = tid; i < NCAND; i += THREADS) {
        keyA[i] = spanse[idxB[i] >> 3];
        if (i >= (int)nv) out[i] = 0.0f;
    }
    __syncthreads();

    // ---- greedy suppression: wave 0, scalar coverage bitmap ----
    if (tid < 64) {
        const int lane = tid;
        uint64_t Bm[8] = {0, 0, 0, 0, 0, 0, 0, 0};   // wave-uniform coverage
        const int nchunk = ((int)nv + 63) >> 6;

        for (int c = 0; c < nchunk; ++c) {
            int i = c * 64 + lane;
            uint32_t k = keyB[i];
            uint32_t se = keyA[i];
            bool valid = k < 0x00800000u;
            float score = 0.0f;
            if (valid) score = -__uint_as_float(~(k + 0x407FFFFFu));

            int s = (int)(se & 0xFFFFu);
            int e = (int)(se >> 16);
            int w0 = s >> 6, w1 = e >> 6;             // width <= 10 -> w1 <= w0+1
            uint64_t m0 = (~0ull) << (s & 63);
            uint64_t m1 = (~0ull) >> (63 - (e & 63));
            if (w0 == w1) { m0 &= m1; m1 = 0ull; }

            // initial conflict vs current coverage (8-way select of scalar words)
            uint64_t bs0 = 0, bs1 = 0;
            #pragma unroll
            for (int w = 0; w < 8; ++w) {
                bs0 = (w0 == w) ? Bm[w] : bs0;
                bs1 = (w1 == w) ? Bm[w] : bs1;
            }
            uint64_t conf = (m0 & bs0) | (m1 & bs1);

            bool undecided = valid;
            bool keep = false;
            while (true) {
                uint64_t cand = __ballot(undecided && conf == 0ull);
                if (cand == 0ull) break;   // all pending conflict (or none pending)
                int jl = __ffsll((unsigned long long)cand) - 1;
                if (undecided && lane <= jl) {
                    undecided = false;
                    keep = (lane == jl);
                }
                // broadcast winner's packed span via one readlane (wave-uniform)
                uint32_t sew = (uint32_t)__builtin_amdgcn_readlane((int)se, jl);
                uint32_t ss = sew & 0xFFFFu, ee = sew >> 16;
                int sw0 = (int)(ss >> 6), sw1 = (int)(ee >> 6);
                uint64_t sm0 = (~0ull) << (ss & 63u);
                uint64_t sm1 = (~0ull) >> (63u - (ee & 63u));
                if (sw0 == sw1) { sm0 &= sm1; sm1 = 0ull; }
                // grow scalar bitmap
                #pragma unroll
                for (int w = 0; w < 8; ++w) {
                    uint64_t add = ((sw0 == w) ? sm0 : 0ull) | ((sw1 == w) ? sm1 : 0ull);
                    Bm[w] |= add;
                }
                // incremental per-lane conflict update
                uint64_t d0 = ((w0 == sw0) ? sm0 : 0ull) | ((w0 == sw1) ? sm1 : 0ull);
                uint64_t d1 = ((w1 == sw0) ? sm0 : 0ull) | ((w1 == sw1) ? sm1 : 0ull);
                conf |= (m0 & d0) | (m1 & d1);
            }
            out[i] = keep ? score : 0.0f;
        }
    }
}

extern "C" void kernel_launch(void* const* d_in, const int* in_sizes, int n_in,
                              void* d_out, int out_size, void* d_ws, size_t ws_size,
                              hipStream_t stream) {
    const float* probs = (const float*)d_in[0];
    const int* spans = (const int*)d_in[1];
    float* out = (float*)d_out;
    int B = in_sizes[0] / NCAND;   // 4
    decoder_kernel<<<dim3(B), dim3(THREADS), 0, stream>>>(probs, spans, out);
}

// Round 4
// 99.521 us; speedup vs baseline: 2.7423x; 1.2613x over previous
//
#include <hip/hip_runtime.h>
#include <stdint.h>

// Greedy flat span-NMS decoder, round 4.
// Key identity: all 8 entity candidates of a span share one interval, and a
// span overlaps itself => at most one candidate/span is ever kept (the span's
// best valid candidate), and keep decisions = span-level greedy NMS on spans
// ordered by their best candidate key. So:
//   1. span_key = min over 8 entities of ((k24<<13)|cand_idx)  (registers only)
//   2. 3-pass stable ballot-radix sort of 1024 span keys (1 elem/thread)
//   3. wave-0 ballot greedy over sorted spans (<=16 chunks), scalar bitmap;
//      concurrently waves 1-15 bucket-scatter all 8192 candidates
//      (2048-bucket counting structure) for rank computation
//   4. rank(kept c) = bucketPrefix + #smaller-in-bucket; out[rank]=score.

#define NSPAN 1024
#define NENT  8
#define NCAND 8192
#define THREADS 1024
#define NWAVE 16

__global__ __launch_bounds__(THREADS)
void decoder_kernel(const float* __restrict__ gprobs,
                    const int* __restrict__ gspans,
                    float* __restrict__ gout) {
    __shared__ uint32_t keyC[NCAND];      // 32 KiB  per-candidate k24
    __shared__ uint64_t spanKeyA[NSPAN];  // 8 KiB
    __shared__ uint64_t spanKeyB[NSPAN];  // 8 KiB
    __shared__ uint32_t whist[NWAVE*256]; // 16 KiB  radix hist; reused as bucket cursors
    __shared__ uint32_t spanse[NSPAN];    // 4 KiB   start | end<<16
    __shared__ uint32_t sorted_se[NSPAN]; // 4 KiB   se per sorted span pos
    __shared__ uint32_t bhist[2048];      // 8 KiB   bucket counts (valid cands)
    __shared__ uint32_t boffs[2048];      // 8 KiB   bucket exclusive prefix
    __shared__ uint32_t barr[NCAND];      // 32 KiB  bucketed packed25 keys
    __shared__ uint64_t keptKey[512];     // 4 KiB   kept span keys (K <= 510)
    __shared__ uint32_t wpart[NWAVE], wexc[NWAVE];
    __shared__ uint32_t nvs_sh, keptCnt;

    const int tid = threadIdx.x;
    const int b = blockIdx.x;
    const int W = tid >> 6;
    const int L = tid & 63;

    // ---------------- P0: load, build keys, zero everything ----------------
    {
        int s = gspans[(size_t)b * NSPAN * 2 + 2 * tid];
        int e = gspans[(size_t)b * NSPAN * 2 + 2 * tid + 1];
        spanse[tid] = (uint32_t)s | ((uint32_t)e << 16);
    }
    const float* probs = gprobs + (size_t)b * NCAND;
    const float4* p4 = (const float4*)probs;
    float4 pa = p4[tid * 2];
    float4 pb = p4[tid * 2 + 1];
    float pv[8] = {pa.x, pa.y, pa.z, pa.w, pb.x, pb.y, pb.z, pb.w};
    uint32_t k24[8];
    uint64_t skey = ~0ull;
    #pragma unroll
    for (int s = 0; s < 8; ++s) {
        bool valid = pv[s] > 0.5f;
        uint32_t u = ~__float_as_uint(-pv[s]);   // valid: [0x407FFFFF,0x40FFFFFE]
        uint32_t k = valid ? (u - 0x407FFFFFu) : 0x00FFFFFFu;  // 24-bit, asc = score desc
        k24[s] = k;
        keyC[tid * 8 + s] = k;
        uint64_t ck = ((uint64_t)k << 13) | (uint32_t)(tid * 8 + s);
        skey = (ck < skey) ? ck : skey;
    }
    spanKeyA[tid] = skey;                        // span-id order = idx order (stable base)
    #pragma unroll
    for (int q = 0; q < 4; ++q) whist[q * 1024 + tid] = 0;
    bhist[tid] = 0; bhist[1024 + tid] = 0;
    if (tid == 0) { nvs_sh = 0; keptCnt = 0; }
    {   // zero output now; ordered before final scatter by later barriers
        float4 z = make_float4(0.f, 0.f, 0.f, 0.f);
        float4* o4 = (float4*)(gout + (size_t)b * NCAND);
        o4[tid] = z; o4[THREADS + tid] = z;
    }
    __syncthreads();

    // ---------------- P1: 3-pass stable radix sort of 1024 span keys --------
    for (int p = 0; p < 3; ++p) {
        uint64_t* src = (p & 1) ? spanKeyB : spanKeyA;
        uint64_t* dst = (p & 1) ? spanKeyA : spanKeyB;
        uint64_t kk = src[tid];
        uint32_t d = (uint32_t)(kk >> (13 + 8 * p)) & 255u;
        uint64_t m = ~0ull;
        #pragma unroll
        for (int bb = 0; bb < 8; ++bb) {
            uint64_t bal = __ballot((d >> bb) & 1u);
            m &= ((d >> bb) & 1u) ? bal : ~bal;
        }
        uint32_t lower = __builtin_amdgcn_mbcnt_hi((uint32_t)(m >> 32),
                         __builtin_amdgcn_mbcnt_lo((uint32_t)m, 0u));
        if (lower == 0) whist[W * 256 + d] = (uint32_t)__popcll(m);
        __syncthreads();
        // exclusive scan of 4096 counters, flat f = d*16 + W (digit-major, wave)
        {
            int f0 = 4 * tid;
            uint32_t v0 = whist[((f0 + 0) & 15) * 256 + ((f0 + 0) >> 4)];
            uint32_t v1 = whist[((f0 + 1) & 15) * 256 + ((f0 + 1) >> 4)];
            uint32_t v2 = whist[((f0 + 2) & 15) * 256 + ((f0 + 2) >> 4)];
            uint32_t v3 = whist[((f0 + 3) & 15) * 256 + ((f0 + 3) >> 4)];
            uint32_t t01 = v0 + v1, t012 = t01 + v2, tot = t012 + v3;
            uint32_t x = tot;
            #pragma unroll
            for (int off = 1; off < 64; off <<= 1) {
                uint32_t y = __shfl_up(x, off, 64);
                if (L >= off) x += y;
            }
            if (L == 63) wpart[W] = x;
            __syncthreads();
            if (tid < 16) {
                uint32_t v = wpart[tid], xx = v;
                #pragma unroll
                for (int off = 1; off < 16; off <<= 1) {
                    uint32_t y = __shfl_up(xx, off, 64);
                    if (tid >= off) xx += y;
                }
                wexc[tid] = xx - v;
            }
            __syncthreads();
            uint32_t ex = wexc[W] + (x - tot);
            whist[((f0 + 0) & 15) * 256 + ((f0 + 0) >> 4)] = ex;
            whist[((f0 + 1) & 15) * 256 + ((f0 + 1) >> 4)] = ex + v0;
            whist[((f0 + 2) & 15) * 256 + ((f0 + 2) >> 4)] = ex + t01;
            whist[((f0 + 3) & 15) * 256 + ((f0 + 3) >> 4)] = ex + t012;
        }
        __syncthreads();
        dst[whist[W * 256 + d] + lower] = kk;
        __syncthreads();
        if (p < 2) {
            #pragma unroll
            for (int q = 0; q < 4; ++q) whist[q * 1024 + tid] = 0;
            __syncthreads();
        }
    }
    // sorted span keys in spanKeyB

    // ---------------- P2: sorted se gather, valid-span count, bucket hist ---
    {
        uint64_t sk = spanKeyB[tid];
        uint32_t sidx = (uint32_t)sk & 8191u;
        sorted_se[tid] = spanse[sidx >> 3];
        bool vs = (uint32_t)(sk >> 13) < 0x800000u;
        uint64_t bv = __ballot(vs);
        if (L == 0) atomicAdd((unsigned int*)&nvs_sh, (unsigned int)__popcll(bv));
    }
    #pragma unroll
    for (int s = 0; s < 8; ++s) {
        uint32_t k = k24[s];
        if (k < 0x800000u) atomicAdd((unsigned int*)&bhist[k >> 12], 1u);
    }
    __syncthreads();

    // ---------------- P3: bucket exclusive scan + cursor init ---------------
    {
        int f0 = 2 * tid;
        uint32_t v0 = bhist[f0], v1 = bhist[f0 + 1];
        uint32_t tot = v0 + v1, x = tot;
        #pragma unroll
        for (int off = 1; off < 64; off <<= 1) {
            uint32_t y = __shfl_up(x, off, 64);
            if (L >= off) x += y;
        }
        if (L == 63) wpart[W] = x;
        __syncthreads();
        if (tid < 16) {
            uint32_t v = wpart[tid], xx = v;
            #pragma unroll
            for (int off = 1; off < 16; off <<= 1) {
                uint32_t y = __shfl_up(xx, off, 64);
                if (tid >= off) xx += y;
            }
            wexc[tid] = xx - v;
        }
        __syncthreads();
        uint32_t ex = wexc[W] + (x - tot);
        boffs[f0] = ex; boffs[f0 + 1] = ex + v0;
    }
    __syncthreads();
    whist[tid] = boffs[tid];                 // reuse whist[0..2047] as cursors
    whist[1024 + tid] = boffs[1024 + tid];
    __syncthreads();

    // ---------------- P4: wave0 greedy || waves 1-15 bucket scatter ---------
    const uint32_t nvs = nvs_sh;
    if (W == 0) {
        uint64_t Bm[8] = {0, 0, 0, 0, 0, 0, 0, 0};  // coverage bitmap (wave-uniform)
        uint32_t K = 0;
        int nchunk = ((int)nvs + 63) >> 6;
        for (int c = 0; c < nchunk; ++c) {
            int i = c * 64 + L;
            uint64_t sk = spanKeyB[i];
            uint32_t se = sorted_se[i];
            bool valid = (uint32_t)(sk >> 13) < 0x800000u;

            int s = (int)(se & 0xFFFFu);
            int e = (int)(se >> 16);
            int w0 = s >> 6, w1 = e >> 6;           // e <= 509 -> words < 8
            uint64_t m0 = (~0ull) << (s & 63);
            uint64_t m1 = (~0ull) >> (63 - (e & 63));
            if (w0 == w1) { m0 &= m1; m1 = 0ull; }

            uint64_t bs0 = 0, bs1 = 0;
            #pragma unroll
            for (int w = 0; w < 8; ++w) {
                bs0 = (w0 == w) ? Bm[w] : bs0;
                bs1 = (w1 == w) ? Bm[w] : bs1;
            }
            uint64_t conf = (m0 & bs0) | (m1 & bs1);
            bool undecided = valid;

            while (true) {
                uint64_t cand = __ballot(undecided && conf == 0ull);
                if (cand == 0ull) break;
                int jl = __ffsll((unsigned long long)cand) - 1;
                if (undecided && L <= jl) {
                    undecided = false;
                    if (L == jl) keptKey[K] = sk;   // winner records itself
                }
                K++;
                uint32_t sew = (uint32_t)__builtin_amdgcn_readlane((int)se, jl);
                uint32_t ss = sew & 0xFFFFu, ee = sew >> 16;
                int sw0 = (int)(ss >> 6), sw1 = (int)(ee >> 6);
                uint64_t sm0 = (~0ull) << (ss & 63u);
                uint64_t sm1 = (~0ull) >> (63u - (ee & 63u));
                if (sw0 == sw1) { sm0 &= sm1; sm1 = 0ull; }
                #pragma unroll
                for (int w = 0; w < 8; ++w) {
                    uint64_t add = ((sw0 == w) ? sm0 : 0ull) | ((sw1 == w) ? sm1 : 0ull);
                    Bm[w] |= add;
                }
                uint64_t d0 = ((w0 == sw0) ? sm0 : 0ull) | ((w0 == sw1) ? sm1 : 0ull);
                uint64_t d1 = ((w1 == sw0) ? sm0 : 0ull) | ((w1 == sw1) ? sm1 : 0ull);
                conf |= (m0 & d0) | (m1 & d1);
            }
        }
        if (L == 0) keptCnt = K;
    } else {
        // scatter all 8192 candidates into buckets (packed 25-bit residual)
        for (int i = tid - 64; i < NCAND; i += THREADS - 64) {
            uint32_t k = keyC[i];
            if (k < 0x800000u) {
                uint32_t pos = atomicAdd((unsigned int*)&whist[k >> 12], 1u);
                barr[pos] = ((k & 0xFFFu) << 13) | (uint32_t)i;
            }
        }
    }
    __syncthreads();

    // ---------------- P5: ranks of kept candidates + output scatter ---------
    if (tid < (int)keptCnt) {
        uint64_t kk = keptKey[tid];
        uint32_t idx = (uint32_t)kk & 8191u;
        uint32_t kv = (uint32_t)(kk >> 13) & 0xFFFFFFu;
        uint32_t bkt = kv >> 12;
        uint32_t lo = ((kv & 0xFFFu) << 13) | idx;
        uint32_t beg = boffs[bkt];
        uint32_t cnt = bhist[bkt];
        uint32_t r = beg;
        for (uint32_t j = 0; j < cnt; ++j) r += (barr[beg + j] < lo) ? 1u : 0u;
        uint32_t u = kv + 0x407FFFFFu;
        float score = -__uint_as_float(~u);      // exact inverse of key build
        gout[(size_t)b * NCAND + r] = score;
    }
}

extern "C" void kernel_launch(void* const* d_in, const int* in_sizes, int n_in,
                              void* d_out, int out_size, void* d_ws, size_t ws_size,
                              hipStream_t stream) {
    const float* probs = (const float*)d_in[0];
    const int* spans = (const int*)d_in[1];
    float* out = (float*)d_out;
    int B = in_sizes[0] / NCAND;   // 4
    decoder_kernel<<<dim3(B), dim3(THREADS), 0, stream>>>(probs, spans, out);
}

// Round 5
// 96.400 us; speedup vs baseline: 2.8311x; 1.0324x over previous
//
#include <hip/hip_runtime.h>
#include <stdint.h>

// Greedy flat span-NMS decoder, round 5.
// Identity (round 4): all 8 entity candidates of a span share one interval and
// a span overlaps itself => greedy == span-level NMS on spans keyed by each
// span's best valid candidate; kept candidate's output slot = its rank among
// all valid candidates (stable by candidate index).
// This round: single-pass COUNTING sort replaces the 3-pass radix, and all
// bucket structures share one histogram + one fused scan + one scatter array:
//   counters C[0..1023]   = span buckets   (k24 >> 13, ~1 valid span/bucket)
//   counters C[1024..3071]= cand buckets   (k24 >> 12, ~2 valid cands/bucket)
//   exclusive scan of the concatenation => span offsets in [0,nvs),
//   candidate offsets in [nvs, nvs+nvc) -- both index ONE scat[] array.
// Within-bucket rank: owner thread compares its packed residual key against
// its (avg ~1-2) bucket peers. 8 barriers total (was ~25).

#define NSPAN 1024
#define NENT  8
#define NCAND 8192
#define THREADS 1024
#define NWAVE 16
#define NCNT 3072
#define SCATMAX (NSPAN + NCAND)   // worst case: every span + candidate valid

__global__ __launch_bounds__(THREADS)
void decoder_kernel(const float* __restrict__ gprobs,
                    const int* __restrict__ gspans,
                    float* __restrict__ gout) {
    __shared__ uint32_t cnt_[NCNT];       // 12 KiB pristine bucket counts
    __shared__ uint32_t cur_[NCNT];       // 12 KiB scanned offsets -> cursors
    __shared__ uint32_t scat[SCATMAX];    // 36 KiB span keys ++ cand packed keys
    __shared__ uint64_t sortedCand[NSPAN];// 8 KiB  (k24<<13)|candidx, sorted spans
    __shared__ uint32_t sortedSE[NSPAN];  // 4 KiB  se per sorted span
    __shared__ uint64_t keptKey[512];     // 4 KiB  kept span keys (K <= 511)
    __shared__ uint32_t wpart[NWAVE], wexc[NWAVE];
    __shared__ uint32_t nvs_sh, keptCnt;

    const int tid = threadIdx.x;
    const int b = blockIdx.x;
    const int W = tid >> 6;
    const int L = tid & 63;

    // ---------------- P0: zero counters; load; build keys -------------------
    cnt_[tid] = 0; cnt_[1024 + tid] = 0; cnt_[2048 + tid] = 0;
    if (tid == 0) keptCnt = 0;

    int s0 = gspans[(size_t)b * NSPAN * 2 + 2 * tid];
    int e0 = gspans[(size_t)b * NSPAN * 2 + 2 * tid + 1];
    const uint32_t myse = (uint32_t)s0 | ((uint32_t)e0 << 16);

    const float4* p4 = (const float4*)(gprobs + (size_t)b * NCAND);
    float4 pa = p4[tid * 2], pb = p4[tid * 2 + 1];
    float pv[8] = {pa.x, pa.y, pa.z, pa.w, pb.x, pb.y, pb.z, pb.w};

    {   // zero the output region (re-poisoned 0xAA before every launch)
        float4 z = make_float4(0.f, 0.f, 0.f, 0.f);
        float4* o4 = (float4*)(gout + (size_t)b * NCAND);
        o4[tid] = z; o4[THREADS + tid] = z;
    }

    uint32_t k24[8];
    uint64_t skey = ~0ull;                 // span best candidate key
    #pragma unroll
    for (int s = 0; s < 8; ++s) {
        bool valid = pv[s] > 0.5f;
        uint32_t u = ~__float_as_uint(-pv[s]);   // valid: [0x407FFFFF,0x40FFFFFE]
        uint32_t k = valid ? (u - 0x407FFFFFu) : 0xFFFFFFu;  // valid < 0x800000
        k24[s] = k;
        uint64_t ck = ((uint64_t)k << 13) | (uint32_t)(tid * 8 + s);
        skey = (ck < skey) ? ck : skey;
    }
    const uint32_t sk24 = (uint32_t)(skey >> 13);
    const bool spanValid = sk24 < 0x800000u;
    __syncthreads();                                         // B1

    // ---------------- P1: fused histogram (span + cand buckets) -------------
    if (spanValid) atomicAdd(&cnt_[sk24 >> 13], 1u);
    #pragma unroll
    for (int s = 0; s < 8; ++s)
        if (k24[s] < 0x800000u) atomicAdd(&cnt_[1024 + (k24[s] >> 12)], 1u);
    __syncthreads();                                         // B2

    // ---------------- P2: fused exclusive scan of 3072 counters -------------
    {
        uint32_t v0 = cnt_[3 * tid], v1 = cnt_[3 * tid + 1], v2 = cnt_[3 * tid + 2];
        uint32_t t01 = v0 + v1, tot = t01 + v2;
        uint32_t x = tot;
        #pragma unroll
        for (int off = 1; off < 64; off <<= 1) {
            uint32_t y = __shfl_up(x, off, 64);
            if (L >= off) x += y;
        }
        if (L == 63) wpart[W] = x;
        __syncthreads();                                     // B3
        if (tid < 16) {
            uint32_t v = wpart[tid], xx = v;
            #pragma unroll
            for (int off = 1; off < 16; off <<= 1) {
                uint32_t y = __shfl_up(xx, off, 64);
                if (tid >= off) xx += y;
            }
            wexc[tid] = xx - v;
        }
        __syncthreads();                                     // B4
        uint32_t ex = wexc[W] + (x - tot);
        cur_[3 * tid] = ex;
        cur_[3 * tid + 1] = ex + v0;
        cur_[3 * tid + 2] = ex + t01;
        // element 1024's exclusive prefix == number of valid spans
        if (3 * tid <= 1024 && 1024 < 3 * tid + 3) {
            uint32_t nv = (1024 == 3 * tid) ? ex : ((1024 == 3 * tid + 1) ? ex + v0 : ex + t01);
            nvs_sh = nv;
        }
    }
    __syncthreads();                                         // B5

    // ---------------- P3: scatter spans + candidates into buckets -----------
    if (spanValid) {
        uint32_t pos = atomicAdd(&cur_[sk24 >> 13], 1u);
        scat[pos] = ((sk24 & 0x1FFFu) << 10) | (uint32_t)tid;      // res13|spanid
    }
    #pragma unroll
    for (int s = 0; s < 8; ++s) {
        uint32_t k = k24[s];
        if (k < 0x800000u) {
            uint32_t pos = atomicAdd(&cur_[1024 + (k >> 12)], 1u);
            scat[pos] = ((k & 0xFFFu) << 13) | (uint32_t)(tid * 8 + s); // res12|idx
        }
    }
    __syncthreads();                                         // B6

    // ---------------- P4: within-bucket rank -> sorted span list ------------
    const uint32_t nvs = nvs_sh;
    if (spanValid) {
        uint32_t bkt = sk24 >> 13;
        uint32_t c = cnt_[bkt];
        uint32_t beg = cur_[bkt] - c;                        // cursor - count
        uint32_t mykey = ((sk24 & 0x1FFFu) << 10) | (uint32_t)tid;
        uint32_t r = 0;
        for (uint32_t j = 0; j < c; ++j) r += (scat[beg + j] < mykey) ? 1u : 0u;
        sortedCand[beg + r] = skey;
        sortedSE[beg + r] = myse;
    }
    __syncthreads();                                         // B7

    // ---------------- P5: wave-0 ballot greedy over sorted spans ------------
    if (W == 0) {
        uint64_t Bm[8] = {0, 0, 0, 0, 0, 0, 0, 0};           // coverage bitmap
        uint32_t K = 0;
        int nchunk = ((int)nvs + 63) >> 6;
        for (int c = 0; c < nchunk; ++c) {
            int i = c * 64 + L;
            bool valid = i < (int)nvs;
            uint64_t sk = sortedCand[i];
            uint32_t se = sortedSE[i];

            int s = (int)(se & 0xFFFFu);
            int e = (int)(se >> 16);
            int w0 = s >> 6, w1 = e >> 6;
            uint64_t m0 = (~0ull) << (s & 63);
            uint64_t m1 = (~0ull) >> (63 - (e & 63));
            if (w0 == w1) { m0 &= m1; m1 = 0ull; }

            uint64_t bs0 = 0, bs1 = 0;
            #pragma unroll
            for (int w = 0; w < 8; ++w) {
                bs0 = (w0 == w) ? Bm[w] : bs0;
                bs1 = (w1 == w) ? Bm[w] : bs1;
            }
            uint64_t conf = (m0 & bs0) | (m1 & bs1);
            bool undecided = valid;

            while (true) {
                uint64_t cand = __ballot(undecided && conf == 0ull);
                if (cand == 0ull) break;
                int jl = __ffsll((unsigned long long)cand) - 1;
                if (undecided && L <= jl) {
                    undecided = false;
                    if (L == jl) keptKey[K] = sk;            // winner records itself
                }
                K++;
                uint32_t sew = (uint32_t)__builtin_amdgcn_readlane((int)se, jl);
                uint32_t ss = sew & 0xFFFFu, ee = sew >> 16;
                int sw0 = (int)(ss >> 6), sw1 = (int)(ee >> 6);
                uint64_t sm0 = (~0ull) << (ss & 63u);
                uint64_t sm1 = (~0ull) >> (63u - (ee & 63u));
                if (sw0 == sw1) { sm0 &= sm1; sm1 = 0ull; }
                #pragma unroll
                for (int w = 0; w < 8; ++w) {
                    uint64_t add = ((sw0 == w) ? sm0 : 0ull) | ((sw1 == w) ? sm1 : 0ull);
                    Bm[w] |= add;
                }
                uint64_t d0 = ((w0 == sw0) ? sm0 : 0ull) | ((w0 == sw1) ? sm1 : 0ull);
                uint64_t d1 = ((w1 == sw0) ? sm0 : 0ull) | ((w1 == sw1) ? sm1 : 0ull);
                conf |= (m0 & d0) | (m1 & d1);
            }
        }
        if (L == 0) keptCnt = K;
    }
    __syncthreads();                                         // B8

    // ---------------- P6: kept-candidate global rank -> output --------------
    if (tid < (int)keptCnt) {
        uint64_t kk = keptKey[tid];
        uint32_t idx = (uint32_t)kk & 8191u;
        uint32_t kv = (uint32_t)(kk >> 13);                  // 24-bit, < 0x800000
        uint32_t bkt = 1024 + (kv >> 12);
        uint32_t c = cnt_[bkt];
        uint32_t beg = cur_[bkt] - c;
        uint32_t mykey = ((kv & 0xFFFu) << 13) | idx;
        uint32_t r = 0;
        for (uint32_t j = 0; j < c; ++j) r += (scat[beg + j] < mykey) ? 1u : 0u;
        uint32_t outpos = (beg - nvs) + r;                   // rank among valid cands
        float score = -__uint_as_float(~(kv + 0x407FFFFFu));
        gout[(size_t)b * NCAND + outpos] = score;
    }
}

extern "C" void kernel_launch(void* const* d_in, const int* in_sizes, int n_in,
                              void* d_out, int out_size, void* d_ws, size_t ws_size,
                              hipStream_t stream) {
    const float* probs = (const float*)d_in[0];
    const int* spans = (const int*)d_in[1];
    float* out = (float*)d_out;
    int B = in_sizes[0] / NCAND;   // 4
    decoder_kernel<<<dim3(B), dim3(THREADS), 0, stream>>>(probs, spans, out);
}

// Round 6
// 95.191 us; speedup vs baseline: 2.8670x; 1.0127x over previous
//
#include <hip/hip_runtime.h>
#include <stdint.h>

// Greedy flat span-NMS decoder, round 6.
// Same math as round 5 (verified): span-level greedy NMS on spans keyed by
// their best valid candidate; kept candidate's output slot = rank among all
// valid candidates via a 2048-bucket counting structure sharing one histogram
// + one fused scan with the 1024 span buckets.
// Schedule changes: 512 threads / 8 waves (2 spans, 16 cands each); candidate
// bucket scatter overlapped with wave-0 greedy (wave0's own cand keys staged
// in LDS); single-barrier two-level scan. 7 barriers total.

#define NSPAN 1024
#define NENT  8
#define NCAND 8192
#define THREADS 512
#define NWAVE 8
#define NCNT 3072
#define SCATMAX (NSPAN + NCAND)

__global__ __launch_bounds__(THREADS)
void decoder_kernel(const float* __restrict__ gprobs,
                    const int* __restrict__ gspans,
                    float* __restrict__ gout) {
    __shared__ uint32_t cnt_[NCNT];        // 12 KiB pristine bucket counts
    __shared__ uint32_t cur_[NCNT];        // 12 KiB scanned offsets -> cursors
    __shared__ uint32_t scat[SCATMAX];     // 36 KiB span keys ++ cand packed keys
    __shared__ uint32_t keyC0[1024];       // 4 KiB  wave0's candidate k24s
    __shared__ uint64_t sortedCand[NSPAN]; // 8 KiB  sorted span best-cand keys
    __shared__ uint32_t sortedSE[NSPAN];   // 4 KiB  se per sorted span
    __shared__ uint64_t keptKey[512];      // 4 KiB  kept span keys (K <= 512)
    __shared__ uint32_t wpart[NWAVE];
    __shared__ uint32_t nvs_sh, keptCnt;

    const int tid = threadIdx.x;
    const int b = blockIdx.x;
    const int W = tid >> 6;
    const int L = tid & 63;

    // ---------------- P0: zero counters; load; build keys -------------------
    #pragma unroll
    for (int q = 0; q < 6; ++q) cnt_[tid + 512 * q] = 0;
    if (tid == 0) keptCnt = 0;

    const int4 sv = ((const int4*)(gspans + (size_t)b * NSPAN * 2))[tid];
    const uint32_t se0 = (uint32_t)sv.x | ((uint32_t)sv.y << 16);
    const uint32_t se1 = (uint32_t)sv.z | ((uint32_t)sv.w << 16);

    const float4* p4 = (const float4*)(gprobs + (size_t)b * NCAND);
    float4 q0 = p4[tid * 4 + 0], q1 = p4[tid * 4 + 1];
    float4 q2 = p4[tid * 4 + 2], q3 = p4[tid * 4 + 3];
    float pv[16] = {q0.x, q0.y, q0.z, q0.w, q1.x, q1.y, q1.z, q1.w,
                    q2.x, q2.y, q2.z, q2.w, q3.x, q3.y, q3.z, q3.w};

    {   // zero the output region (re-poisoned 0xAA before every launch)
        float4 z = make_float4(0.f, 0.f, 0.f, 0.f);
        float4* o4 = (float4*)(gout + (size_t)b * NCAND);
        #pragma unroll
        for (int q = 0; q < 4; ++q) o4[tid + 512 * q] = z;
    }

    uint32_t k24[16];
    uint64_t skey0 = ~0ull, skey1 = ~0ull;   // span best-candidate keys
    #pragma unroll
    for (int s = 0; s < 16; ++s) {
        bool valid = pv[s] > 0.5f;
        uint32_t u = ~__float_as_uint(-pv[s]);   // valid: [0x407FFFFF,0x40FFFFFE]
        uint32_t k = valid ? (u - 0x407FFFFFu) : 0xFFFFFFu;  // valid < 0x800000
        k24[s] = k;
        uint64_t ck = ((uint64_t)k << 13) | (uint32_t)(tid * 16 + s);
        if (s < 8) skey0 = (ck < skey0) ? ck : skey0;
        else       skey1 = (ck < skey1) ? ck : skey1;
    }
    if (W == 0) {   // stage wave0's cand keys (global idx 0..1023) for others
        #pragma unroll
        for (int s = 0; s < 16; ++s) keyC0[tid * 16 + s] = k24[s];
    }
    const uint32_t sk0 = (uint32_t)(skey0 >> 13);
    const uint32_t sk1 = (uint32_t)(skey1 >> 13);
    const bool sv0 = sk0 < 0x800000u, sv1 = sk1 < 0x800000u;
    __syncthreads();                                         // B1

    // ---------------- P1: fused histogram (span + cand buckets) -------------
    if (sv0) atomicAdd(&cnt_[sk0 >> 13], 1u);
    if (sv1) atomicAdd(&cnt_[sk1 >> 13], 1u);
    #pragma unroll
    for (int s = 0; s < 16; ++s)
        if (k24[s] < 0x800000u) atomicAdd(&cnt_[1024 + (k24[s] >> 12)], 1u);
    __syncthreads();                                         // B2

    // ---------------- P2: fused exclusive scan of 3072 counters -------------
    {
        int f0 = 6 * tid;
        uint32_t v, ps[7];
        ps[0] = 0;
        #pragma unroll
        for (int j = 0; j < 6; ++j) { v = cnt_[f0 + j]; ps[j + 1] = ps[j] + v; }
        uint32_t tot = ps[6], x = tot;
        #pragma unroll
        for (int off = 1; off < 64; off <<= 1) {
            uint32_t y = __shfl_up(x, off, 64);
            if (L >= off) x += y;
        }
        if (L == 63) wpart[W] = x;
        __syncthreads();                                     // B3
        uint32_t wex = 0;
        #pragma unroll
        for (int w = 0; w < NWAVE; ++w) wex += (w < W) ? wpart[w] : 0u;
        uint32_t ex = wex + (x - tot);
        #pragma unroll
        for (int j = 0; j < 6; ++j) cur_[f0 + j] = ex + ps[j];
        if (f0 <= 1024 && 1024 < f0 + 6) {   // exclusive prefix at counter 1024
            uint32_t d = (uint32_t)(1024 - f0);
            uint32_t nv = ps[0];
            #pragma unroll
            for (int j = 1; j < 6; ++j) nv = (d == (uint32_t)j) ? ps[j] : nv;
            nvs_sh = ex + nv;                // = number of valid spans
        }
    }
    __syncthreads();                                         // B4

    // ---------------- P3: scatter spans into buckets -------------------------
    if (sv0) {
        uint32_t pos = atomicAdd(&cur_[sk0 >> 13], 1u);
        scat[pos] = ((sk0 & 0x1FFFu) << 10) | (uint32_t)(2 * tid);
    }
    if (sv1) {
        uint32_t pos = atomicAdd(&cur_[sk1 >> 13], 1u);
        scat[pos] = ((sk1 & 0x1FFFu) << 10) | (uint32_t)(2 * tid + 1);
    }
    __syncthreads();                                         // B5

    // ---------------- P4: within-bucket rank -> sorted span list ------------
    const uint32_t nvs = nvs_sh;
    if (sv0) {
        uint32_t bkt = sk0 >> 13;
        uint32_t c = cnt_[bkt];
        uint32_t beg = cur_[bkt] - c;
        uint32_t mykey = ((sk0 & 0x1FFFu) << 10) | (uint32_t)(2 * tid);
        uint32_t r = 0;
        if (c > 1) for (uint32_t j = 0; j < c; ++j) r += (scat[beg + j] < mykey) ? 1u : 0u;
        sortedCand[beg + r] = skey0;
        sortedSE[beg + r] = se0;
    }
    if (sv1) {
        uint32_t bkt = sk1 >> 13;
        uint32_t c = cnt_[bkt];
        uint32_t beg = cur_[bkt] - c;
        uint32_t mykey = ((sk1 & 0x1FFFu) << 10) | (uint32_t)(2 * tid + 1);
        uint32_t r = 0;
        if (c > 1) for (uint32_t j = 0; j < c; ++j) r += (scat[beg + j] < mykey) ? 1u : 0u;
        sortedCand[beg + r] = skey1;
        sortedSE[beg + r] = se1;
    }
    __syncthreads();                                         // B6

    // -------- P5: wave-0 ballot greedy  ||  waves 1-7 cand bucket scatter ----
    if (W == 0) {
        uint64_t Bm[8] = {0, 0, 0, 0, 0, 0, 0, 0};           // coverage bitmap
        uint32_t K = 0;
        int nchunk = ((int)nvs + 63) >> 6;
        for (int c = 0; c < nchunk; ++c) {
            int i = c * 64 + L;
            bool valid = i < (int)nvs;
            uint64_t sk = sortedCand[i];
            uint32_t se = sortedSE[i];

            int s = (int)(se & 0xFFFFu);
            int e = (int)(se >> 16);
            int w0 = s >> 6, w1 = e >> 6;                    // e <= 509 -> < 8
            uint64_t m0 = (~0ull) << (s & 63);
            uint64_t m1 = (~0ull) >> (63 - (e & 63));
            if (w0 == w1) { m0 &= m1; m1 = 0ull; }

            uint64_t bs0 = 0, bs1 = 0;
            #pragma unroll
            for (int w = 0; w < 8; ++w) {
                bs0 = (w0 == w) ? Bm[w] : bs0;
                bs1 = (w1 == w) ? Bm[w] : bs1;
            }
            uint64_t conf = (m0 & bs0) | (m1 & bs1);
            bool undecided = valid;

            while (true) {
                uint64_t cand = __ballot(undecided && conf == 0ull);
                if (cand == 0ull) break;
                int jl = __ffsll((unsigned long long)cand) - 1;
                if (undecided && L <= jl) {
                    undecided = false;
                    if (L == jl) keptKey[K] = sk;            // winner records itself
                }
                K++;
                uint32_t sew = (uint32_t)__builtin_amdgcn_readlane((int)se, jl);
                uint32_t ss = sew & 0xFFFFu, ee = sew >> 16;
                int sw0 = (int)(ss >> 6), sw1 = (int)(ee >> 6);
                uint64_t sm0 = (~0ull) << (ss & 63u);
                uint64_t sm1 = (~0ull) >> (63u - (ee & 63u));
                if (sw0 == sw1) { sm0 &= sm1; sm1 = 0ull; }
                #pragma unroll
                for (int w = 0; w < 8; ++w) {
                    uint64_t add = ((sw0 == w) ? sm0 : 0ull) | ((sw1 == w) ? sm1 : 0ull);
                    Bm[w] |= add;
                }
                uint64_t d0 = ((w0 == sw0) ? sm0 : 0ull) | ((w0 == sw1) ? sm1 : 0ull);
                uint64_t d1 = ((w1 == sw0) ? sm0 : 0ull) | ((w1 == sw1) ? sm1 : 0ull);
                conf |= (m0 & d0) | (m1 & d1);
            }
        }
        if (L == 0) keptCnt = K;
    } else {
        // own 16 candidates (from registers)
        #pragma unroll
        for (int s = 0; s < 16; ++s) {
            uint32_t k = k24[s];
            if (k < 0x800000u) {
                uint32_t pos = atomicAdd(&cur_[1024 + (k >> 12)], 1u);
                scat[pos] = ((k & 0xFFFu) << 13) | (uint32_t)(tid * 16 + s);
            }
        }
        // wave0's 1024 staged candidates
        for (int i = tid - 64; i < 1024; i += THREADS - 64) {
            uint32_t k = keyC0[i];
            if (k < 0x800000u) {
                uint32_t pos = atomicAdd(&cur_[1024 + (k >> 12)], 1u);
                scat[pos] = ((k & 0xFFFu) << 13) | (uint32_t)i;
            }
        }
    }
    __syncthreads();                                         // B7

    // ---------------- P6: kept-candidate global rank -> output --------------
    if (tid < (int)keptCnt) {
        uint64_t kk = keptKey[tid];
        uint32_t idx = (uint32_t)kk & 8191u;
        uint32_t kv = (uint32_t)(kk >> 13) & 0xFFFFFFu;      // < 0x800000
        uint32_t bkt = 1024 + (kv >> 12);
        uint32_t c = cnt_[bkt];
        uint32_t beg = cur_[bkt] - c;
        uint32_t mykey = ((kv & 0xFFFu) << 13) | idx;
        uint32_t r = 0;
        for (uint32_t j = 0; j < c; ++j) r += (scat[beg + j] < mykey) ? 1u : 0u;
        uint32_t outpos = (beg - nvs_sh) + r;                // rank among valid cands
        float score = -__uint_as_float(~(kv + 0x407FFFFFu));
        gout[(size_t)b * NCAND + outpos] = score;
    }
}

extern "C" void kernel_launch(void* const* d_in, const int* in_sizes, int n_in,
                              void* d_out, int out_size, void* d_ws, size_t ws_size,
                              hipStream_t stream) {
    const float* probs = (const float*)d_in[0];
    const int* spans = (const int*)d_in[1];
    float* out = (float*)d_out;
    int B = in_sizes[0] / NCAND;   // 4
    decoder_kernel<<<dim3(B), dim3(THREADS), 0, stream>>>(probs, spans, out);
}

// Round 7
// 82.972 us; speedup vs baseline: 3.2892x; 1.1473x over previous
//
#include <hip/hip_runtime.h>
#include <stdint.h>

// Greedy flat span-NMS decoder, round 7.
// Same math as rounds 5/6 (verified): span-level greedy NMS on spans keyed by
// their best valid candidate; kept candidate's output slot = rank among all
// valid candidates via a 2048-bucket counting structure sharing one histogram
// + one fused scan with the 1024 span buckets.
// Round-7 change: fast-chain greedy. Per-winner serial chain is now
//   ffs -> readlane(packed se) -> 2x v_cmp (interval overlap vs winner) ->
//   cand &= ~lowmask & ~ov            (~15 dependent cycles, was ~45)
// Coverage bitmap only matters at chunk boundaries -> its per-winner fold is
// off the critical chain. Keep bookkeeping via scalar keepmask + compaction.
// Chunk LDS loads are double-buffered.

#define NSPAN 1024
#define NENT  8
#define NCAND 8192
#define THREADS 512
#define NWAVE 8
#define NCNT 3072
#define SCATMAX (NSPAN + NCAND)

__global__ __launch_bounds__(THREADS)
void decoder_kernel(const float* __restrict__ gprobs,
                    const int* __restrict__ gspans,
                    float* __restrict__ gout) {
    __shared__ uint32_t cnt_[NCNT];        // 12 KiB pristine bucket counts
    __shared__ uint32_t cur_[NCNT];        // 12 KiB scanned offsets -> cursors
    __shared__ uint32_t scat[SCATMAX];     // 36 KiB span keys ++ cand packed keys
    __shared__ uint32_t keyC0[1024];       // 4 KiB  wave0's candidate k24s
    __shared__ uint64_t sortedCand[NSPAN]; // 8 KiB  sorted span best-cand keys
    __shared__ uint32_t sortedSE[NSPAN];   // 4 KiB  se per sorted span
    __shared__ uint64_t keptKey[512];      // 4 KiB  kept span keys (K <= 512)
    __shared__ uint32_t wpart[NWAVE];
    __shared__ uint32_t nvs_sh, keptCnt;

    const int tid = threadIdx.x;
    const int b = blockIdx.x;
    const int W = tid >> 6;
    const int L = tid & 63;

    // ---------------- P0: zero counters; load; build keys -------------------
    #pragma unroll
    for (int q = 0; q < 6; ++q) cnt_[tid + 512 * q] = 0;
    if (tid == 0) keptCnt = 0;

    const int4 sv = ((const int4*)(gspans + (size_t)b * NSPAN * 2))[tid];
    const uint32_t se0 = (uint32_t)sv.x | ((uint32_t)sv.y << 16);
    const uint32_t se1 = (uint32_t)sv.z | ((uint32_t)sv.w << 16);

    const float4* p4 = (const float4*)(gprobs + (size_t)b * NCAND);
    float4 q0 = p4[tid * 4 + 0], q1 = p4[tid * 4 + 1];
    float4 q2 = p4[tid * 4 + 2], q3 = p4[tid * 4 + 3];
    float pv[16] = {q0.x, q0.y, q0.z, q0.w, q1.x, q1.y, q1.z, q1.w,
                    q2.x, q2.y, q2.z, q2.w, q3.x, q3.y, q3.z, q3.w};

    {   // zero the output region (re-poisoned 0xAA before every launch)
        float4 z = make_float4(0.f, 0.f, 0.f, 0.f);
        float4* o4 = (float4*)(gout + (size_t)b * NCAND);
        #pragma unroll
        for (int q = 0; q < 4; ++q) o4[tid + 512 * q] = z;
    }

    uint32_t k24[16];
    uint64_t skey0 = ~0ull, skey1 = ~0ull;   // span best-candidate keys
    #pragma unroll
    for (int s = 0; s < 16; ++s) {
        bool valid = pv[s] > 0.5f;
        uint32_t u = ~__float_as_uint(-pv[s]);   // valid: [0x407FFFFF,0x40FFFFFE]
        uint32_t k = valid ? (u - 0x407FFFFFu) : 0xFFFFFFu;  // valid < 0x800000
        k24[s] = k;
        uint64_t ck = ((uint64_t)k << 13) | (uint32_t)(tid * 16 + s);
        if (s < 8) skey0 = (ck < skey0) ? ck : skey0;
        else       skey1 = (ck < skey1) ? ck : skey1;
    }
    if (W == 0) {   // stage wave0's cand keys (global idx 0..1023) for others
        #pragma unroll
        for (int s = 0; s < 16; ++s) keyC0[tid * 16 + s] = k24[s];
    }
    const uint32_t sk0 = (uint32_t)(skey0 >> 13);
    const uint32_t sk1 = (uint32_t)(skey1 >> 13);
    const bool sv0 = sk0 < 0x800000u, sv1 = sk1 < 0x800000u;
    __syncthreads();                                         // B1

    // ---------------- P1: fused histogram (span + cand buckets) -------------
    if (sv0) atomicAdd(&cnt_[sk0 >> 13], 1u);
    if (sv1) atomicAdd(&cnt_[sk1 >> 13], 1u);
    #pragma unroll
    for (int s = 0; s < 16; ++s)
        if (k24[s] < 0x800000u) atomicAdd(&cnt_[1024 + (k24[s] >> 12)], 1u);
    __syncthreads();                                         // B2

    // ---------------- P2: fused exclusive scan of 3072 counters -------------
    {
        int f0 = 6 * tid;
        uint32_t v, ps[7];
        ps[0] = 0;
        #pragma unroll
        for (int j = 0; j < 6; ++j) { v = cnt_[f0 + j]; ps[j + 1] = ps[j] + v; }
        uint32_t tot = ps[6], x = tot;
        #pragma unroll
        for (int off = 1; off < 64; off <<= 1) {
            uint32_t y = __shfl_up(x, off, 64);
            if (L >= off) x += y;
        }
        if (L == 63) wpart[W] = x;
        __syncthreads();                                     // B3
        uint32_t wex = 0;
        #pragma unroll
        for (int w = 0; w < NWAVE; ++w) wex += (w < W) ? wpart[w] : 0u;
        uint32_t ex = wex + (x - tot);
        #pragma unroll
        for (int j = 0; j < 6; ++j) cur_[f0 + j] = ex + ps[j];
        if (f0 <= 1024 && 1024 < f0 + 6) {   // exclusive prefix at counter 1024
            uint32_t d = (uint32_t)(1024 - f0);
            uint32_t nv = ps[0];
            #pragma unroll
            for (int j = 1; j < 6; ++j) nv = (d == (uint32_t)j) ? ps[j] : nv;
            nvs_sh = ex + nv;                // = number of valid spans
        }
    }
    __syncthreads();                                         // B4

    // ---------------- P3: scatter spans into buckets -------------------------
    if (sv0) {
        uint32_t pos = atomicAdd(&cur_[sk0 >> 13], 1u);
        scat[pos] = ((sk0 & 0x1FFFu) << 10) | (uint32_t)(2 * tid);
    }
    if (sv1) {
        uint32_t pos = atomicAdd(&cur_[sk1 >> 13], 1u);
        scat[pos] = ((sk1 & 0x1FFFu) << 10) | (uint32_t)(2 * tid + 1);
    }
    __syncthreads();                                         // B5

    // ---------------- P4: within-bucket rank -> sorted span list ------------
    const uint32_t nvs = nvs_sh;
    if (sv0) {
        uint32_t bkt = sk0 >> 13;
        uint32_t c = cnt_[bkt];
        uint32_t beg = cur_[bkt] - c;
        uint32_t mykey = ((sk0 & 0x1FFFu) << 10) | (uint32_t)(2 * tid);
        uint32_t r = 0;
        if (c > 1) for (uint32_t j = 0; j < c; ++j) r += (scat[beg + j] < mykey) ? 1u : 0u;
        sortedCand[beg + r] = skey0;
        sortedSE[beg + r] = se0;
    }
    if (sv1) {
        uint32_t bkt = sk1 >> 13;
        uint32_t c = cnt_[bkt];
        uint32_t beg = cur_[bkt] - c;
        uint32_t mykey = ((sk1 & 0x1FFFu) << 10) | (uint32_t)(2 * tid + 1);
        uint32_t r = 0;
        if (c > 1) for (uint32_t j = 0; j < c; ++j) r += (scat[beg + j] < mykey) ? 1u : 0u;
        sortedCand[beg + r] = skey1;
        sortedSE[beg + r] = se1;
    }
    __syncthreads();                                         // B6

    // -------- P5: wave-0 fast-chain greedy || waves 1-7 cand bucket scatter --
    if (W == 0) {
        uint64_t Bm[8] = {0, 0, 0, 0, 0, 0, 0, 0};   // coverage (chunk granularity)
        uint32_t K0 = 0;
        int nchunk = ((int)nvs + 63) >> 6;
        uint64_t sk = sortedCand[L];
        uint32_t se = sortedSE[L];
        for (int c = 0; c < nchunk; ++c) {
            // double-buffer: issue next chunk's LDS loads now
            uint64_t sk_n = 0; uint32_t se_n = 0;
            if (c + 1 < nchunk) {
                sk_n = sortedCand[(c + 1) * 64 + L];
                se_n = sortedSE[(c + 1) * 64 + L];
            }
            uint32_t s_v = se & 0xFFFFu, e_v = se >> 16;
            // conf0 vs coverage bitmap (once per chunk)
            int w0 = (int)(s_v >> 6), w1 = (int)(e_v >> 6);
            uint64_t m0 = (~0ull) << (s_v & 63u);
            uint64_t m1 = (~0ull) >> (63u - (e_v & 63u));
            if (w0 == w1) { m0 &= m1; m1 = 0ull; }
            uint64_t bs0 = 0, bs1 = 0;
            #pragma unroll
            for (int w = 0; w < 8; ++w) {
                bs0 = (w0 == w) ? Bm[w] : bs0;
                bs1 = (w1 == w) ? Bm[w] : bs1;
            }
            bool conf0 = ((m0 & bs0) | (m1 & bs1)) != 0ull;
            bool valid = (c * 64 + L) < (int)nvs;

            uint64_t cand = __ballot(valid && !conf0);
            uint64_t keepmask = 0;
            while (cand) {
                int jl = __ffsll((unsigned long long)cand) - 1;
                uint32_t sew = (uint32_t)__builtin_amdgcn_readlane((int)se, jl);
                uint32_t ss = sew & 0xFFFFu, ee = sew >> 16;
                // overlap with winner: (ss <= e_v) && (s_v <= ee)
                uint64_t ov = __ballot(e_v >= ss && s_v <= ee);
                keepmask |= 1ull << jl;                       // off-chain
                cand &= ~((2ull << jl) - 1ull);               // drop lanes <= jl
                cand &= ~ov;                                  // drop new conflicts
                // fold winner into coverage bitmap (off the serial chain)
                int sw0 = (int)(ss >> 6), sw1 = (int)(ee >> 6);
                uint64_t sm0 = (~0ull) << (ss & 63u);
                uint64_t sm1 = (~0ull) >> (63u - (ee & 63u));
                if (sw0 == sw1) { sm0 &= sm1; sm1 = 0ull; }
                #pragma unroll
                for (int w = 0; w < 8; ++w) {
                    uint64_t add = ((sw0 == w) ? sm0 : 0ull) | ((sw1 == w) ? sm1 : 0ull);
                    Bm[w] |= add;
                }
            }
            // compact this chunk's winners into keptKey (order irrelevant for P6)
            if ((keepmask >> L) & 1ull) {
                uint32_t pos = K0 + (uint32_t)__popcll(keepmask & ((1ull << L) - 1ull));
                keptKey[pos] = sk;
            }
            K0 += (uint32_t)__popcll(keepmask);
            sk = sk_n; se = se_n;
        }
        if (L == 0) keptCnt = K0;
    } else {
        // own 16 candidates (from registers)
        #pragma unroll
        for (int s = 0; s < 16; ++s) {
            uint32_t k = k24[s];
            if (k < 0x800000u) {
                uint32_t pos = atomicAdd(&cur_[1024 + (k >> 12)], 1u);
                scat[pos] = ((k & 0xFFFu) << 13) | (uint32_t)(tid * 16 + s);
            }
        }
        // wave0's 1024 staged candidates
        for (int i = tid - 64; i < 1024; i += THREADS - 64) {
            uint32_t k = keyC0[i];
            if (k < 0x800000u) {
                uint32_t pos = atomicAdd(&cur_[1024 + (k >> 12)], 1u);
                scat[pos] = ((k & 0xFFFu) << 13) | (uint32_t)i;
            }
        }
    }
    __syncthreads();                                         // B7

    // ---------------- P6: kept-candidate global rank -> output --------------
    if (tid < (int)keptCnt) {
        uint64_t kk = keptKey[tid];
        uint32_t idx = (uint32_t)kk & 8191u;
        uint32_t kv = (uint32_t)(kk >> 13) & 0xFFFFFFu;      // < 0x800000
        uint32_t bkt = 1024 + (kv >> 12);
        uint32_t c = cnt_[bkt];
        uint32_t beg = cur_[bkt] - c;
        uint32_t mykey = ((kv & 0xFFFu) << 13) | idx;
        uint32_t r = 0;
        for (uint32_t j = 0; j < c; ++j) r += (scat[beg + j] < mykey) ? 1u : 0u;
        uint32_t outpos = (beg - nvs_sh) + r;                // rank among valid cands
        float score = -__uint_as_float(~(kv + 0x407FFFFFu));
        gout[(size_t)b * NCAND + outpos] = score;
    }
}

extern "C" void kernel_launch(void* const* d_in, const int* in_sizes, int n_in,
                              void* d_out, int out_size, void* d_ws, size_t ws_size,
                              hipStream_t stream) {
    const float* probs = (const float*)d_in[0];
    const int* spans = (const int*)d_in[1];
    float* out = (float*)d_out;
    int B = in_sizes[0] / NCAND;   // 4
    decoder_kernel<<<dim3(B), dim3(THREADS), 0, stream>>>(probs, spans, out);
}